// Round 12
// baseline (674.236 us; speedup 1.0000x reference)
//
#include <hip/hip_runtime.h>

#define N_NODES 10242
#define NNZ_E   71694
#define NNZ_PAD_MAX (NNZ_E + N_NODES)       // rows padded to multiple of 2
#define BT      32      // B*T
#define C_IN    16
#define K_S     20
#define C_OUT   32
#define F       512     // BT * C_IN
typedef unsigned short u16;
typedef unsigned int   u32;

#define RING_ELEMS ((size_t)N_NODES * F)    // f16 elems per ring slot, layout [n][bt*16+c]
#define RING_BYTES (RING_ELEMS * 2)         // ~10.5 MB
#define R_SLOTS    10                       // ring slots -> 2 proj passes

typedef __attribute__((ext_vector_type(8)))  _Float16 half8;
typedef __attribute__((ext_vector_type(16))) float    float16;

__device__ __forceinline__ void unpack8h(uint4 u, float* f) {
    union { uint4 u; _Float16 h[8]; } v; v.u = u;
    #pragma unroll
    for (int i = 0; i < 8; ++i) f[i] = (float)v.h[i];
}
__device__ __forceinline__ uint4 pack8h(const float* f) {
    union { uint4 u; _Float16 h[8]; } v;
    #pragma unroll
    for (int i = 0; i < 8; ++i) v.h[i] = (_Float16)f[i];
    return v.u;
}
__device__ __forceinline__ u16 f2h(float f) {
    union { _Float16 h; u16 u; } v; v.h = (_Float16)f; return v.u;
}

// ---------------- fused CSR build: one block, LDS-resident -----------------
// count -> scan(padded x2) -> scatter(eidx) -> per-row sort -> fill cpack
// Deterministic: canonical order = ascending original edge index.

__global__ __launch_bounds__(1024) void csr_build_kernel(
        const int* __restrict__ erow, const int* __restrict__ ecol,
        const float* __restrict__ eval,
        int* __restrict__ row_ptr, int* __restrict__ eidx,
        int2* __restrict__ cpack) {
    __shared__ int cur[N_NODES];      // counts, then cursor (41 KB)
    __shared__ int part[1024];
    int t = threadIdx.x;

    for (int i = t; i < N_NODES; i += 1024) cur[i] = 0;
    __syncthreads();
    for (int e = t; e < NNZ_E; e += 1024) atomicAdd(&cur[erow[e]], 1);
    __syncthreads();

    const int chunk = (N_NODES + 1023) / 1024;   // 11
    int base = t * chunk;
    int s = 0;
    for (int i = 0; i < chunk; ++i) {
        int idx = base + i;
        if (idx < N_NODES) s += (cur[idx] + 1) & ~1;
    }
    part[t] = s;
    __syncthreads();
    for (int off = 1; off < 1024; off <<= 1) {
        int v = (t >= off) ? part[t - off] : 0;
        __syncthreads();
        part[t] += v;
        __syncthreads();
    }
    int run = (t == 0) ? 0 : part[t - 1];
    for (int i = 0; i < chunk; ++i) {
        int idx = base + i;
        if (idx < N_NODES) {
            int c = cur[idx];
            row_ptr[idx] = run;
            cur[idx] = run;            // cursor = start
            run += (c + 1) & ~1;
        }
    }
    if (base <= N_NODES && N_NODES < base + chunk) row_ptr[N_NODES] = run;
    __syncthreads();

    for (int e = t; e < NNZ_E; e += 1024) {
        int p = atomicAdd(&cur[erow[e]], 1);
        eidx[p] = e;
    }
    __syncthreads();

    for (int r = t; r < N_NODES; r += 1024) {
        int st = row_ptr[r];
        int en = cur[r];               // start + real count
        int pe = row_ptr[r + 1];       // padded end
        for (int i = st + 1; i < en; ++i) {
            int key = eidx[i];
            int j = i - 1;
            while (j >= st && eidx[j] > key) { eidx[j + 1] = eidx[j]; --j; }
            eidx[j + 1] = key;
        }
        for (int p = st; p < en; ++p) {
            int ed = eidx[p];
            cpack[p] = make_int2(ecol[ed], __float_as_int(eval[ed]));
        }
        for (int p = en; p < pe; ++p) cpack[p] = make_int2(0, 0);  // pad: row0, w=0
    }
}

// ---------------- transform: x (fp32) -> ring slot 0 (f16), + wtfrag -------
// ring layout: T[n][bt*16 + c]
// wtfrag (verified round 6): lane L, reg j ->
//   B[k=8*(L>>5)+j][col=L&31] = W[cout=col][c=k][k_cheb]

__global__ __launch_bounds__(256) void transform_kernel(
        const float* __restrict__ x, const float* __restrict__ W,
        u16* __restrict__ T0, u16* __restrict__ wtfrag) {
    int g = blockIdx.x * 256 + threadIdx.x;   // grid covers N*F exactly
    if (g < K_S * 512) {
        int j    = g & 7;
        int lane = (g >> 3) & 63;
        int k    = g >> 9;
        int cout = lane & 31;
        int c    = ((lane >> 5) << 3) + j;
        wtfrag[g] = f2h(W[cout * (C_IN * K_S) + c * K_S + k]);
    }
    int n   = g >> 9;
    int rem = g & 511;
    int bt  = rem >> 4;
    int c   = rem & 15;
    float v = x[((size_t)bt * N_NODES + n) * C_IN + c];
    T0[(size_t)n * F + rem] = f2h(v);
}

// ---------------- Chebyshev step: wave-per-node, f16 ring, fp32 math -------
// dst = alpha * L @ srcB + beta * srcA   (all ring slots f16)

__global__ __launch_bounds__(64) void spmm_step_kernel(
        const u16* __restrict__ srcB, const u16* __restrict__ srcA,
        u16* __restrict__ dst,
        const int* __restrict__ row_ptr, const int2* __restrict__ cpack,
        float alpha, float beta) {
    int n = blockIdx.x;                   // block-uniform -> scalar loads
    int lane = threadIdx.x;
    int s = row_ptr[n], e_end = row_ptr[n + 1];   // padded, multiple of 2

    // hoist srcA load (independent; overlaps gather)
    float a[8] = {0, 0, 0, 0, 0, 0, 0, 0};
    if (beta != 0.f) {
        uint4 ua = ((const uint4*)(srcA + (size_t)n * F))[lane];
        unpack8h(ua, a);
    }

    float acc0[8] = {0, 0, 0, 0, 0, 0, 0, 0};
    float acc1[8] = {0, 0, 0, 0, 0, 0, 0, 0};

    for (int e = s; e < e_end; e += 2) {
        int2 p0 = cpack[e], p1 = cpack[e + 1];
        uint4 g0 = ((const uint4*)(srcB + (size_t)p0.x * F))[lane];
        uint4 g1 = ((const uint4*)(srcB + (size_t)p1.x * F))[lane];
        float b0[8], b1[8];
        unpack8h(g0, b0); unpack8h(g1, b1);
        float v0 = __int_as_float(p0.y), v1 = __int_as_float(p1.y);
        #pragma unroll
        for (int i = 0; i < 8; ++i) {
            acc0[i] += v0 * b0[i];
            acc1[i] += v1 * b1[i];
        }
    }

    float y[8];
    #pragma unroll
    for (int i = 0; i < 8; ++i)
        y[i] = alpha * (acc0[i] + acc1[i]) + beta * a[i];

    ((uint4*)(dst + (size_t)n * F))[lane] = pack8h(y);
}

// ---------------- MFMA projection over a chunk (kcnt <= 10), f16 -----------
// per wave: one node; tile M=32(bt) x N=32(cout), K=kcnt*16.
// A: m=L&31, kk=8*(L>>5)+j ; C/D: col=L&31, row=(reg&3)+8*(reg>>2)+4*(L>>5)
// (layouts verified round 6; C/D dtype-independent)

__global__ __launch_bounds__(256) void proj_mfma_kernel(
        const u16* __restrict__ ring, int k0, int kcnt,
        const u16* __restrict__ wtfrag, float* __restrict__ out, int accumulate) {
    int wave = threadIdx.x >> 6;
    int lane = threadIdx.x & 63;
    int n = blockIdx.x * 4 + wave;
    if (n >= N_NODES) return;

    int col = lane & 31;
    int grp = lane >> 5;
    size_t aoff = (size_t)n * F + (size_t)col * 16 + grp * 8;

    union uv { uint4 u; half8 h; };
    uv av, bv;
    av.u = *(const uint4*)(ring + (size_t)(k0 % R_SLOTS) * RING_ELEMS + aoff);
    bv.u = *(const uint4*)(wtfrag + (size_t)k0 * 512 + lane * 8);

    float16 acc = {};
    for (int j = 0; j < kcnt; ++j) {
        uv an = av, bn = bv;
        if (j + 1 < kcnt) {
            int k = k0 + j + 1;
            an.u = *(const uint4*)(ring + (size_t)(k % R_SLOTS) * RING_ELEMS + aoff);
            bn.u = *(const uint4*)(wtfrag + (size_t)k * 512 + lane * 8);
        }
        acc = __builtin_amdgcn_mfma_f32_32x32x16_f16(av.h, bv.h, acc, 0, 0, 0);
        av = an; bv = bn;
    }

    #pragma unroll
    for (int r = 0; r < 16; ++r) {
        int bt = (r & 3) + 8 * (r >> 2) + 4 * grp;
        float* op = out + ((size_t)bt * N_NODES + n) * C_OUT + col;
        if (accumulate) *op += acc[r];
        else            *op  = acc[r];
    }
}

// ---------------- host launch ----------------

extern "C" void kernel_launch(void* const* d_in, const int* in_sizes, int n_in,
                              void* d_out, int out_size, void* d_ws, size_t ws_size,
                              hipStream_t stream) {
    const float* x    = (const float*)d_in[0];
    const int*   erow = (const int*)  d_in[1];
    const int*   ecol = (const int*)  d_in[2];
    const float* eval = (const float*)d_in[3];
    const float* W    = (const float*)d_in[4];
    float* out = (float*)d_out;

    char* ws = (char*)d_ws;
    size_t o = 0;
    auto alloc = [&](size_t bytes) -> char* {
        o = (o + 511) & ~(size_t)511;
        char* r = ws + o;
        o += bytes;
        return r;
    };
    int*   row_ptr = (int*)  alloc((size_t)(N_NODES + 1) * 4);
    int*   eidx    = (int*)  alloc((size_t)NNZ_PAD_MAX * 4);
    int2*  cpack   = (int2*) alloc((size_t)NNZ_PAD_MAX * 8);
    u16*   wtfrag  = (u16*)  alloc((size_t)K_S * 512 * 2);
    u16*   ring    = (u16*)  alloc((size_t)R_SLOTS * RING_BYTES);   // ~105 MB
    auto slot = [&](int k) -> u16* { return ring + (size_t)(k % R_SLOTS) * RING_ELEMS; };

    // fused CSR build (deterministic) — one dispatch
    csr_build_kernel<<<1, 1024, 0, stream>>>(erow, ecol, eval, row_ptr, eidx, cpack);

    // transform + wtfrag — one dispatch
    transform_kernel<<<(int)(RING_ELEMS / 256), 256, 0, stream>>>(x, W, slot(0), wtfrag);

    const int proj_blocks = (N_NODES + 3) / 4;
    int c0 = 0;
    auto maybe_pass = [&](int k_done) {
        int target = K_S - c0;
        if (target > R_SLOTS) target = R_SLOTS;
        if (target > 0 && (k_done - c0 + 1) == target) {
            proj_mfma_kernel<<<proj_blocks, 256, 0, stream>>>(
                slot(0) ? ring : ring, c0, target, wtfrag, out, (c0 > 0) ? 1 : 0);
            c0 += target;
        }
    };

    maybe_pass(0);   // no-op (target=10, k_done=0) — kept for clarity

    // T1 = L T0 ; Tk = 2 L T_{k-1} - T_{k-2}
    for (int k = 1; k < K_S; ++k) {
        const u16* srcB = slot(k - 1);
        const u16* srcA = (k >= 2) ? slot(k - 2) : slot(k - 1);  // unread when beta==0
        float alpha = (k == 1) ? 1.f : 2.f;
        float beta  = (k == 1) ? 0.f : -1.f;
        spmm_step_kernel<<<N_NODES, 64, 0, stream>>>(
            srcB, srcA, slot(k), row_ptr, cpack, alpha, beta);
        maybe_pass(k);
    }
}